// Round 4
// baseline (389.096 us; speedup 1.0000x reference)
//
#include <hip/hip_runtime.h>
#include <hip/hip_bf16.h>

// LFA_self — 3-kernel pipeline for MI355X.
// Algebra: scores = Xq (Wq Wk^T) Xk^T + g(t2) (bq term; bk term is softmax-
// invariant); out = attn . (Xv (Wv Wo)) + (bv Wo + bo).
// K1: split-K partial scores -> ws. K2: reduce+softmax -> attn fp32 + bf16
// tile. K3: per-(b,h,128-col-chunk) attn.Z with dense float4 stores.

#define NT 49
#define TOKS 16384
#define HSL 1024
#define SLOT 3200            // floats per partial slot: 49x64 scores + 64 g-tail

typedef __attribute__((ext_vector_type(8))) short bf16x8;
typedef __attribute__((ext_vector_type(4))) float f32x4;

__device__ __forceinline__ ushort f2bf(float f) {
    union { float f; unsigned u; } v; v.f = f;
    return (ushort)((v.u + 0x7fffu + ((v.u >> 16) & 1u)) >> 16);   // RNE
}

// ================= K1: partial scores, grid (b,h,s)=1024, 256 thr ==========
__global__ __launch_bounds__(256, 2) void k_scores(
    const float* __restrict__ qin, const float* __restrict__ kin,
    const float* __restrict__ Wq, const float* __restrict__ bq,
    const float* __restrict__ Wk, float* __restrict__ ws1)
{
    __shared__ ushort bufA[64*128];   // Yq bf16, 256B rows, XOR-swizzled
    __shared__ ushort bufB[64*128];   // Xk bf16
    __shared__ float  Msh[256];       // Wq Wk^T
    __shared__ float  wkbqSh[16];     // Wk bq
    __shared__ float  gSh[64];

    const int tid  = threadIdx.x;
    const int lane = tid & 63;
    const int wv   = tid >> 6;        // 0..3
    const int s    = blockIdx.x & 1;
    const int h    = (blockIdx.x >> 1) & 15;
    const int b    = blockIdx.x >> 5;

    const float* qbase = qin + (size_t)b*NT*TOKS + h*HSL + s*512;
    const float* kbase = kin + (size_t)b*NT*TOKS + h*HSL + s*512;

    {   // init: zero pad rows (49..63 must be 0 for MFMA), weight products
        unsigned* z0 = (unsigned*)bufA; unsigned* z1 = (unsigned*)bufB;
        for (int i = tid; i < 4096; i += 256) { z0[i] = 0u; z1[i] = 0u; }
        const int c1 = tid >> 4, c2 = tid & 15;
        float m = 0.f;
        #pragma unroll
        for (int f = 0; f < 16; ++f) m += Wq[c1*16+f] * Wk[c2*16+f];
        Msh[tid] = m;
        if (tid < 16) {
            float wb = 0.f;
            #pragma unroll
            for (int g = 0; g < 16; ++g) wb += Wk[tid*16+g] * bq[g];
            wkbqSh[tid] = wb;
        }
        if (tid < 64) gSh[tid] = 0.f;
    }
    __syncthreads();

    f32x4 accS[4];
    #pragma unroll
    for (int nt = 0; nt < 4; ++nt) accS[nt] = (f32x4){0.f,0.f,0.f,0.f};

    for (int kc = 0; kc < 4; ++kc) {
        for (int idx = tid; idx < 784; idx += 256) {
            const int isK = idx >= 392;
            const int p   = isK ? idx - 392 : idx;
            const int t   = p >> 3, si = p & 7;
            const float* src = (isK ? kbase : qbase) + (size_t)t*TOKS + (kc*8 + si)*16;
            float x[16];
            *(float4*)(x)     = *(const float4*)(src);
            *(float4*)(x + 4) = *(const float4*)(src + 4);
            *(float4*)(x + 8) = *(const float4*)(src + 8);
            *(float4*)(x +12) = *(const float4*)(src +12);
            unsigned wpk[8];
            if (!isK) {
                #pragma unroll
                for (int c2 = 0; c2 < 16; c2 += 2) {
                    float y0 = 0.f, y1 = 0.f;
                    #pragma unroll
                    for (int c = 0; c < 16; ++c) {
                        y0 += x[c] * Msh[c*16 + c2];
                        y1 += x[c] * Msh[c*16 + c2 + 1];
                    }
                    wpk[c2 >> 1] = (unsigned)f2bf(y0) | ((unsigned)f2bf(y1) << 16);
                }
                const int bo_ = t*256 + si*32, sw = (t & 7) << 4;
                *(uint4*)((char*)bufA + ((bo_     ) ^ sw)) = *(uint4*)(wpk);
                *(uint4*)((char*)bufA + ((bo_ + 16) ^ sw)) = *(uint4*)(wpk + 4);
            } else {
                #pragma unroll
                for (int c = 0; c < 16; c += 2)
                    wpk[c >> 1] = (unsigned)f2bf(x[c]) | ((unsigned)f2bf(x[c+1]) << 16);
                const int bo_ = t*256 + si*32, sw = (t & 7) << 4;
                *(uint4*)((char*)bufB + ((bo_     ) ^ sw)) = *(uint4*)(wpk);
                *(uint4*)((char*)bufB + ((bo_ + 16) ^ sw)) = *(uint4*)(wpk + 4);
                // g(t2) partial (exactly 0 when bq==0; order-independent then)
                float pg = 0.f;
                #pragma unroll
                for (int c = 0; c < 16; ++c) pg += x[c] * wkbqSh[c];
                if (pg != 0.f) atomicAdd(&gSh[t], pg);
            }
        }
        __syncthreads();
        #pragma unroll
        for (int ks = 0; ks < 4; ++ks) {
            const int ra  = wv*16 + (lane & 15);
            const int abo = (ra*256 + (ks*32 + (lane >> 4)*8)*2) ^ ((ra & 7) << 4);
            const bf16x8 af = *(const bf16x8*)((const char*)bufA + abo);
            #pragma unroll
            for (int nt = 0; nt < 4; ++nt) {
                const int rb  = nt*16 + (lane & 15);
                const int bbo = (rb*256 + (ks*32 + (lane >> 4)*8)*2) ^ ((rb & 7) << 4);
                const bf16x8 bf = *(const bf16x8*)((const char*)bufB + bbo);
                accS[nt] = __builtin_amdgcn_mfma_f32_16x16x32_bf16(af, bf, accS[nt], 0, 0, 0);
            }
        }
        __syncthreads();
    }

    float* slot = ws1 + (size_t)blockIdx.x * SLOT;
    #pragma unroll
    for (int nt = 0; nt < 4; ++nt) {
        const int col = nt*16 + (lane & 15);
        #pragma unroll
        for (int r = 0; r < 4; ++r) {
            const int row = wv*16 + (lane >> 4)*4 + r;
            if (row < NT) slot[row*64 + col] = accS[nt][r];
        }
    }
    if (tid < 64) slot[3136 + tid] = gSh[tid];   // gSh final since last barrier
}

// ================= K2: reduce + softmax, grid (b,h)=512, 256 thr ===========
__global__ __launch_bounds__(256, 2) void k_softmax(
    const float* __restrict__ ws1, float* __restrict__ attnp,
    ushort* __restrict__ ws2)
{
    __shared__ float sS[NT*69];       // stride 69: conflict-free row scans
    __shared__ float sG[64];
    const int tid = threadIdx.x;
    const float* slotA = ws1 + (size_t)blockIdx.x * 2 * SLOT;
    const float* slotB = slotA + SLOT;

    for (int p = tid; p < 784; p += 256) {          // 49x64 floats as float4
        const int row = p >> 4, c4 = (p & 15) * 4;
        const float4 a  = *(const float4*)(slotA + row*64 + c4);
        const float4 bb = *(const float4*)(slotB + row*64 + c4);
        sS[row*69 + c4 + 0] = a.x + bb.x;
        sS[row*69 + c4 + 1] = a.y + bb.y;
        sS[row*69 + c4 + 2] = a.z + bb.z;
        sS[row*69 + c4 + 3] = a.w + bb.w;
    }
    if (tid < 64) sG[tid] = slotA[3136 + tid] + slotB[3136 + tid];
    __syncthreads();

    if (tid < NT) {
        float mx = -1e30f;
        for (int j = 0; j < NT; ++j) {
            const float v = (sS[tid*69 + j] + sG[j]) * 0.03125f;
            sS[tid*69 + j] = v;
            mx = fmaxf(mx, v);
        }
        float ssum = 0.f;
        for (int j = 0; j < NT; ++j) {
            const float e = __expf(sS[tid*69 + j] - mx);
            sS[tid*69 + j] = e; ssum += e;
        }
        const float inv = 1.0f / ssum;
        for (int j = 0; j < NT; ++j) sS[tid*69 + j] *= inv;
    }
    __syncthreads();

    float* ab = attnp + (size_t)blockIdx.x * (NT*NT);
    for (int p = tid; p < NT*NT; p += 256) {
        const int t = p / NT, j = p - t*NT;
        ab[p] = sS[t*69 + j];
    }
    ushort* w2 = ws2 + (size_t)blockIdx.x * 4096;   // 64x64 bf16, zero-padded
    for (int p = tid; p < 4096; p += 256) {
        const int t = p >> 6, j = p & 63;
        const float v = (t < NT && j < NT) ? sS[t*69 + j] : 0.f;
        w2[p] = f2bf(v);
    }
}

// ================= K3: out = attn.Z + bvo, grid (b,h,kc)=4096, 256 thr =====
__global__ __launch_bounds__(256, 2) void k_out(
    const float* __restrict__ vin,
    const float* __restrict__ Wv, const float* __restrict__ bv,
    const float* __restrict__ Wo, const float* __restrict__ bo,
    const ushort* __restrict__ ws2, float* __restrict__ out)
{
    __shared__ float blob[NT*132];    // 25.9 KB; Z (16 KB) aliases the front
    __shared__ float WvoSh[256];
    __shared__ float bvoSh[16];
    ushort* Z = (ushort*)blob;        // [64][128] bf16, 256B rows, swizzled

    const int tid  = threadIdx.x;
    const int lane = tid & 63;
    const int wv   = tid >> 6;        // 0..3 -> M-tile
    const int kc   = blockIdx.x & 7;
    const int h    = (blockIdx.x >> 3) & 15;
    const int b    = blockIdx.x >> 7;
    const float* vbase = vin + (size_t)b*NT*TOKS + h*HSL;

    {
        const int c1 = tid >> 4, c2 = tid & 15;
        float wvo = 0.f;
        #pragma unroll
        for (int f = 0; f < 16; ++f) wvo += Wv[c1*16+f] * Wo[f*16+c2];
        WvoSh[tid] = wvo;
        if (tid < 16) {
            float s2 = 0.f;
            #pragma unroll
            for (int g = 0; g < 16; ++g) s2 += bv[g]*Wo[g*16+tid];
            bvoSh[tid] = s2 + bo[tid];
        }
    }
    __syncthreads();   // WvoSh ready before staging uses it

    // stage Z = Xv * Wvo (bf16): 392 real tasks + 120 zero-pad rows = 512
    for (int p = tid; p < 512; p += 256) {
        int t, si;
        unsigned wpk[8];
        if (p < 392) {
            t = p >> 3; si = p & 7;
            const float* src = vbase + (size_t)t*TOKS + (kc*8 + si)*16;
            float x[16];
            *(float4*)(x)     = *(const float4*)(src);
            *(float4*)(x + 4) = *(const float4*)(src + 4);
            *(float4*)(x + 8) = *(const float4*)(src + 8);
            *(float4*)(x +12) = *(const float4*)(src +12);
            #pragma unroll
            for (int c2 = 0; c2 < 16; c2 += 2) {
                float y0 = 0.f, y1 = 0.f;
                #pragma unroll
                for (int c = 0; c < 16; ++c) {
                    y0 += x[c] * WvoSh[c*16 + c2];
                    y1 += x[c] * WvoSh[c*16 + c2 + 1];
                }
                wpk[c2 >> 1] = (unsigned)f2bf(y0) | ((unsigned)f2bf(y1) << 16);
            }
        } else {
            const int r = p - 392;
            t = 49 + (r >> 3); si = r & 7;
            #pragma unroll
            for (int j = 0; j < 8; ++j) wpk[j] = 0u;
        }
        const int bo_ = t*256 + si*32, sw = (t & 7) << 4;
        *(uint4*)((char*)Z + ((bo_     ) ^ sw)) = *(uint4*)(wpk);
        *(uint4*)((char*)Z + ((bo_ + 16) ^ sw)) = *(uint4*)(wpk + 4);
    }

    // A-fragments straight from ws2 (L2-hot 8 KB tile, plain [64][64] layout)
    const ushort* w2 = ws2 + ((size_t)(b*16 + h)) * 4096;
    const int ra = wv*16 + (lane & 15);
    const bf16x8 af0 = *(const bf16x8*)(w2 + ra*64 +      (lane >> 4)*8);
    const bf16x8 af1 = *(const bf16x8*)(w2 + ra*64 + 32 + (lane >> 4)*8);
    __syncthreads();   // Z staged

    f32x4 accV[8];
    #pragma unroll
    for (int nt = 0; nt < 8; ++nt) accV[nt] = (f32x4){0.f,0.f,0.f,0.f};
    #pragma unroll
    for (int ks = 0; ks < 2; ++ks) {
        const bf16x8 af = ks ? af1 : af0;
        #pragma unroll
        for (int nt = 0; nt < 8; ++nt) {
            const int n = nt*16 + (lane & 15);
            bf16x8 bf;
            #pragma unroll
            for (int j = 0; j < 8; ++j) {       // u16 gather: B[k=t2][n=d]
                const int r2  = ks*32 + (lane >> 4)*8 + j;
                const int bo_ = (r2*256 + n*2) ^ ((r2 & 7) << 4);
                bf[j] = *(const short*)((const char*)Z + bo_);
            }
            accV[nt] = __builtin_amdgcn_mfma_f32_16x16x32_bf16(af, bf, accV[nt], 0, 0, 0);
        }
    }
    __syncthreads();   // all Z reads done; blob reusable as fp32 V~

    #pragma unroll
    for (int nt = 0; nt < 8; ++nt) {
        const int n = nt*16 + (lane & 15);
        const float bias = bvoSh[n & 15];
        #pragma unroll
        for (int r = 0; r < 4; ++r) {
            const int row = wv*16 + (lane >> 4)*4 + r;
            if (row < NT) blob[row*132 + n] = accV[nt][r] + bias;
        }
    }
    __syncthreads();

    // dense stores: float4 per lane, lane-contiguous (512B segments per row)
    for (int p = tid; p < 1568; p += 256) {
        const int t = p >> 5, q = p & 31;
        const float4 vv = *(const float4*)&blob[t*132 + q*4];
        float* dst = out + (size_t)(b*NT + t)*TOKS + h*HSL + kc*128 + q*4;
        *(float4*)dst = vv;
    }
}

extern "C" void kernel_launch(void* const* d_in, const int* in_sizes, int n_in,
                              void* d_out, int out_size, void* d_ws, size_t ws_size,
                              hipStream_t stream) {
    const float* v  = (const float*)d_in[0];
    const float* k  = (const float*)d_in[1];
    const float* q  = (const float*)d_in[2];
    const float* Wq = (const float*)d_in[3];
    const float* bq = (const float*)d_in[4];
    const float* Wk = (const float*)d_in[5];
    const float* bk = (const float*)d_in[6];   // softmax-row-invariant; unused
    const float* Wv = (const float*)d_in[7];
    const float* bv = (const float*)d_in[8];
    const float* Wo = (const float*)d_in[9];
    const float* bo = (const float*)d_in[10];
    (void)bk; (void)in_sizes; (void)n_in; (void)ws_size; (void)out_size;

    float*  outp  = (float*)d_out;
    float*  attnp = outp + (size_t)32 * 49 * 16384;     // out | attn concat
    float*  ws1   = (float*)d_ws;                       // 1024*3200 fp32 = 13.1 MB
    ushort* ws2   = (ushort*)(ws1 + (size_t)1024*SLOT); // 512*4096 bf16 = 4 MB

    k_scores <<<dim3(1024), dim3(256), 0, stream>>>(q, k, Wq, bq, Wk, ws1);
    k_softmax<<<dim3(512),  dim3(256), 0, stream>>>(ws1, attnp, ws2);
    k_out    <<<dim3(4096), dim3(256), 0, stream>>>(v, Wv, bv, Wo, bo, ws2, outp);
}